// Round 7
// baseline (164.989 us; speedup 1.0000x reference)
//
#include <hip/hip_runtime.h>

// (B,H,S,D) = (2,16,2048,64), fp32 in/out, causal. Flash-attention fwd.
// Round 9 = Round 8 with the combine-phase barriers changed from inline-asm
// BAR_LGKM to __syncthreads() (full fence around the type-punned f32 reuse
// of the bf16 staging bytes; the only unproven construct in the crashed R8).
// Design (unchanged): residency-flattening. R7 counters showed occupancy 24%
// == 66/32 avg blocks/CU: co-scheduled blocks had 32:1 work spread; short
// blocks die, the 32-iter block finishes alone. Here:
//   block = strip pair (u, 63-u): span (u+1)+(64-u) = 65 tiles, UNIFORM.
//   4 waves split keys round-robin (T = wave, wave+4, ...), each staging
//   its own tile in private 8KB LDS -> ZERO in-loop barriers.
//   4-way additive partials (fixed-shift exp2) combined in LDS per strip;
//   wave 3 (always fewest tiles) is the reducer/storer.
// 1024 uniform blocks x 32KB LDS = 4 blocks/CU flat, no drain tail.
#define SEQ 2048
#define HD  64
#define SCALE 0.18033688011111772f   // 0.125 * log2(e)

typedef __bf16 bf16x8 __attribute__((ext_vector_type(8)));
typedef __bf16 bf16x2 __attribute__((ext_vector_type(2)));
typedef float  f32x4  __attribute__((ext_vector_type(4)));
typedef float  f32x16 __attribute__((ext_vector_type(16)));

union PU { unsigned u[4]; bf16x8 v; };

__device__ __forceinline__ unsigned pk2(float lo, float hi) {
    union { unsigned u; bf16x2 v; } t;
    t.v = bf16x2{(__bf16)lo, (__bf16)hi};
    return t.u;
}

// Swap high half of x (lanes 32-63) with low half of y (lanes 0-31).
__device__ __forceinline__ void plswap(unsigned &x, unsigned &y) {
#if __has_builtin(__builtin_amdgcn_permlane32_swap)
    auto r = __builtin_amdgcn_permlane32_swap(x, y, false, false);
    x = (unsigned)r[0];
    y = (unsigned)r[1];
#else
    asm("v_permlane32_swap_b32 %0, %1" : "+v"(x), "+v"(y));
#endif
}

__global__ __launch_bounds__(256, 4) void attn_fwd(
    const float* __restrict__ Q,
    const float* __restrict__ K,
    const float* __restrict__ V,
    float* __restrict__ O)
{
    // smem: per-wave private staging, 8KB each:
    //   KB[w][32 key][64 d] bf16 (4KB) | Vt[w][64 d][32 key] bf16 (4KB).
    // Combine scratch (barrier-guarded, staging dead): 3 x 2112 f32.
    __shared__ __align__(16) unsigned char smem[32768];
    #define KBw(w,key,c8) ((__bf16*)(smem + ((w)<<13) +        (((key)<<7) + ((c8)<<4))))
    #define VTw(w,r,c8)   ((__bf16*)(smem + ((w)<<13) + 4096 + (((r)<<6)   + ((c8)<<4))))
    #define OSw(w)        ((float*)(smem + (w)*8448))   // w in {0,1,2}

    const int tid  = threadIdx.x;
    const int wave = tid >> 6;      // key-quarter 0..3
    const int lane = tid & 63;
    const int n    = lane & 31;     // MFMA m/n lane index
    const int p    = lane >> 5;     // k-half-of-16 selector

    // Block -> (bh, strip pair). Same-bh blocks map to one XCD (x%8 fixed).
    const int x  = blockIdx.x;
    const int bh = x & 31;
    const int pu = x >> 5;          // strips pu and 63-pu: uniform 65 tiles

    const float* __restrict__ Qh = Q + (size_t)bh * SEQ * HD;
    const float* __restrict__ Kh = K + (size_t)bh * SEQ * HD;
    const float* __restrict__ Vh = V + (size_t)bh * SEQ * HD;
    float* __restrict__       Oh = O + (size_t)bh * SEQ * HD;

    #pragma unroll 1
    for (int half = 0; half < 2; ++half) {
        const int u  = half ? (63 - pu) : pu;   // strip index 0..63
        const int R0 = u * 32;                  // first query row
        const int nt = u + 1;                   // 32-key tiles in causal span

        // ---- Q fragments (B-operand layout), scale pre-folded ----
        bf16x8 qf[4];
        {
            const float* qrow = Qh + (size_t)(R0 + n) * HD;
            #pragma unroll
            for (int c = 0; c < 4; ++c) {
                f32x4 a = *(const f32x4*)(qrow + 16 * c + 8 * p);
                f32x4 b = *(const f32x4*)(qrow + 16 * c + 8 * p + 4);
                #pragma unroll
                for (int j = 0; j < 4; ++j) {
                    qf[c][j]     = (__bf16)(a[j] * SCALE);
                    qf[c][4 + j] = (__bf16)(b[j] * SCALE);
                }
            }
        }

        f32x16 oT[2] = {};      // O^T partial accumulators (d-halves)
        float  l_own = 0.f;     // partial row-sum (this lane's key columns)

        // ---- this wave's tiles: T = wave, wave+4, ... (no barriers) ----
        #pragma unroll 1
        for (int T = wave; T < nt; T += 4) {
            // stage tile T into private LDS (2 rounds = old 128-thread roles)
            #pragma unroll
            for (int t = 0; t < 2; ++t) {
                const int local = lane + (t << 6);
                const int key_s = local >> 2;       // K: key row 0..31
                const int dgi   = local & 3;        // K: 16-float d group
                const int swk   = key_s & 7;
                const float* kp = Kh + (size_t)(32 * T + key_s) * HD + dgi * 16;
                f32x4 k0 = *(const f32x4*)(kp);
                f32x4 k1 = *(const f32x4*)(kp + 4);
                f32x4 k2 = *(const f32x4*)(kp + 8);
                f32x4 k3 = *(const f32x4*)(kp + 12);
                bf16x8 w0, w1;
                #pragma unroll
                for (int j = 0; j < 4; ++j) {
                    w0[j] = (__bf16)k0[j]; w0[4 + j] = (__bf16)k1[j];
                    w1[j] = (__bf16)k2[j]; w1[4 + j] = (__bf16)k3[j];
                }
                *(bf16x8*)KBw(wave, key_s, (2 * dgi)     ^ swk) = w0;
                *(bf16x8*)KBw(wave, key_s, (2 * dgi + 1) ^ swk) = w1;

                const int Ls = local & 31;          // V: d-pair (2Ls, 2Ls+1)
                const int ko = local >> 5;          // V: 8-key group 0..3
                const int swv = Ls & 3;
                const float* vp = Vh + (size_t)(32 * T + 8 * ko) * HD + 2 * Ls;
                float2 vv[8];
                #pragma unroll
                for (int j = 0; j < 8; ++j) vv[j] = *(const float2*)(vp + (size_t)j * HD);
                bf16x8 v0, v1;
                #pragma unroll
                for (int j = 0; j < 8; ++j) { v0[j] = (__bf16)vv[j].x; v1[j] = (__bf16)vv[j].y; }
                *(bf16x8*)VTw(wave, 2 * Ls,     ko ^ swv) = v0;
                *(bf16x8*)VTw(wave, 2 * Ls + 1, ko ^ swv) = v1;
            }
            // same-wave ds_write -> ds_read ordering: compiler-inserted waits

            __builtin_amdgcn_s_setprio(1);
            // ---- S^T = K Q^T ----
            f32x16 sT = {};
            #pragma unroll
            for (int cc = 0; cc < 4; ++cc) {
                bf16x8 kf = *(const bf16x8*)KBw(wave, n, (2 * cc + p) ^ (n & 7));
                sT = __builtin_amdgcn_mfma_f32_32x32x16_bf16(kf, qf[cc], sT, 0, 0, 0);
            }

            const bool diag = (T == u);   // only the span's last tile is masked
            float pv[16];
            float ts = 0.f;
            #pragma unroll
            for (int r = 0; r < 16; ++r) {
                float pe = __builtin_amdgcn_exp2f(sT[r]);   // scale folded into Q
                if (diag) {
                    const int kk = (r & 3) + 8 * (r >> 2) + 4 * p;
                    pe = (kk <= n) ? pe : 0.f;
                }
                pv[r] = pe;
                ts += pe;
            }
            l_own += ts;

            // ---- P: C-layout -> B-layout in-register ----
            unsigned a0 = pk2(pv[0],  pv[1]),  a1 = pk2(pv[2],  pv[3]);
            unsigned a2 = pk2(pv[4],  pv[5]),  a3 = pk2(pv[6],  pv[7]);
            unsigned b0 = pk2(pv[8],  pv[9]),  b1 = pk2(pv[10], pv[11]);
            unsigned b2 = pk2(pv[12], pv[13]), b3 = pk2(pv[14], pv[15]);
            plswap(a0, a2);
            plswap(a1, a3);
            plswap(b0, b2);
            plswap(b1, b3);
            PU pu0, pu1;
            pu0.u[0] = a0; pu0.u[1] = a1; pu0.u[2] = a2; pu0.u[3] = a3;
            pu1.u[0] = b0; pu1.u[1] = b1; pu1.u[2] = b2; pu1.u[3] = b3;
            bf16x8 pf0 = pu0.v;
            bf16x8 pf1 = pu1.v;

            // ---- O^T += V^T P^T ----
            const int swn = (n >> 1) & 3;
            #pragma unroll
            for (int dg = 0; dg < 2; ++dg) {
                bf16x8 vf0 = *(const bf16x8*)VTw(wave, 32 * dg + n, p ^ swn);
                bf16x8 vf1 = *(const bf16x8*)VTw(wave, 32 * dg + n, (2 + p) ^ swn);
                oT[dg] = __builtin_amdgcn_mfma_f32_32x32x16_bf16(vf0, pf0, oT[dg], 0, 0, 0);
                oT[dg] = __builtin_amdgcn_mfma_f32_32x32x16_bf16(vf1, pf1, oT[dg], 0, 0, 0);
            }
            __builtin_amdgcn_s_setprio(0);
        }

        // ---- combine 4 key-quarter partials (additive: fixed-shift) ----
        float l_part = l_own + __shfl_xor(l_own, 32, 64);

        __syncthreads();                // staging dead; full fence (f32 reuse)
        if (wave != 3) {
            #pragma unroll
            for (int dg = 0; dg < 2; ++dg)
                #pragma unroll
                for (int r = 0; r < 16; ++r)
                    OSw(wave)[(dg * 16 + r) * 64 + lane] = oT[dg][r];
            OSw(wave)[2048 + lane] = l_part;
        }
        __syncthreads();                // partials visible
        if (wave == 3) {                // wave 3 always has the fewest tiles
            const float lsum = l_part + OSw(0)[2048 + lane]
                                      + OSw(1)[2048 + lane]
                                      + OSw(2)[2048 + lane];
            const float linv = 1.0f / lsum;
            #pragma unroll
            for (int dg = 0; dg < 2; ++dg) {
                #pragma unroll
                for (int u4 = 0; u4 < 4; ++u4) {
                    f32x4 o;
                    #pragma unroll
                    for (int j = 0; j < 4; ++j) {
                        const int r   = 4 * u4 + j;
                        const int idx = (dg * 16 + r) * 64 + lane;
                        o[j] = (oT[dg][r] + OSw(0)[idx] + OSw(1)[idx] + OSw(2)[idx]) * linv;
                    }
                    *(f32x4*)&Oh[(size_t)(R0 + n) * HD + dg * 32 + u4 * 8 + 4 * p] = o;
                }
            }
        }
        __syncthreads();                // scratch free before next strip stages
    }
}

extern "C" void kernel_launch(void* const* d_in, const int* in_sizes, int n_in,
                              void* d_out, int out_size, void* d_ws, size_t ws_size,
                              hipStream_t stream) {
    const float* Q = (const float*)d_in[0];
    const float* K = (const float*)d_in[1];
    const float* V = (const float*)d_in[2];
    // d_in[3]: causal mask — analytically tril, not read.
    float* O = (float*)d_out;

    dim3 grid(1024);
    dim3 block(256);
    attn_fwd<<<grid, block, 0, stream>>>(Q, K, V, O);
}

// Round 9
// 164.737 us; speedup vs baseline: 1.0015x; 1.0015x over previous
//
#include <hip/hip_runtime.h>

// (B,H,S,D) = (2,16,2048,64), fp32 in/out, causal. Flash-attention fwd.
// Round 10 (resubmit; round-8 bench was GPUAcquisitionTimeout, never ran).
// = R9's uniform wave-autonomous decomposition + the pipeline R9 dropped
// (its measured regression 57->92us: per-iter serial chain
// load->vmcnt->cvt->ds_write->lgkm->ds_read->MFMA with no overlap).
//   - wave-private staging DOUBLE-BUFFERED (2 x 8KB per wave, 64KB/blk):
//     compute reads buf staged LAST iter; stage writes the other buf.
//   - register prefetch one tile ahead: global loads issue a full iteration
//     before their vmcnt wait at stage time.
//   - hot loop has ZERO barriers (all hazards same-wave, in-order ds).
// Decomposition (R9, kept): block = strip pair (u, 63-u), 65 tiles uniform;
// 4 waves round-robin keys (T = wave, wave+4, ...); additive fixed-shift
// partials combined in LDS per strip, wave 3 reduces; 1024 uniform blocks.
// 2 blocks/CU flat (LDS 64KB), 2 scheduling rounds, no drain tail.
#define SEQ 2048
#define HD  64
#define SCALE 0.18033688011111772f   // 0.125 * log2(e)

typedef __bf16 bf16x8 __attribute__((ext_vector_type(8)));
typedef __bf16 bf16x2 __attribute__((ext_vector_type(2)));
typedef float  f32x4  __attribute__((ext_vector_type(4)));
typedef float  f32x16 __attribute__((ext_vector_type(16)));

union PU { unsigned u[4]; bf16x8 v; };

__device__ __forceinline__ unsigned pk2(float lo, float hi) {
    union { unsigned u; bf16x2 v; } t;
    t.v = bf16x2{(__bf16)lo, (__bf16)hi};
    return t.u;
}

// Swap high half of x (lanes 32-63) with low half of y (lanes 0-31).
__device__ __forceinline__ void plswap(unsigned &x, unsigned &y) {
#if __has_builtin(__builtin_amdgcn_permlane32_swap)
    auto r = __builtin_amdgcn_permlane32_swap(x, y, false, false);
    x = (unsigned)r[0];
    y = (unsigned)r[1];
#else
    asm("v_permlane32_swap_b32 %0, %1" : "+v"(x), "+v"(y));
#endif
}

__global__ __launch_bounds__(256, 2) void attn_fwd(
    const float* __restrict__ Q,
    const float* __restrict__ K,
    const float* __restrict__ V,
    float* __restrict__ O)
{
    // smem: per-wave double-buffered staging, 16KB/wave:
    //   [wave][buf]: KB[32 key][64 d] bf16 (4KB) | Vt[64 d][32 key] bf16 (4KB)
    // Combine scratch (barrier-guarded, staging dead): 3 x 2112 f32 = 25KB.
    __shared__ __align__(16) unsigned char smem[65536];
    #define KBw(w,b,key,c8) ((__bf16*)(smem + ((w)<<14) + ((b)<<13) +        (((key)<<7) + ((c8)<<4))))
    #define VTw(w,b,r,c8)   ((__bf16*)(smem + ((w)<<14) + ((b)<<13) + 4096 + (((r)<<6)   + ((c8)<<4))))
    #define OSw(w)          ((float*)(smem + (w)*8448))   // w in {0,1,2}

    const int tid  = threadIdx.x;
    const int wave = tid >> 6;      // key-quarter 0..3
    const int lane = tid & 63;
    const int n    = lane & 31;     // MFMA m/n lane index
    const int p    = lane >> 5;     // k-half-of-16 selector

    // Block -> (bh, strip pair). Same-bh blocks map to one XCD (x%8 fixed).
    const int x  = blockIdx.x;
    const int bh = x & 31;
    const int pu = x >> 5;          // strips pu and 63-pu: uniform 65 tiles

    const float* __restrict__ Qh = Q + (size_t)bh * SEQ * HD;
    const float* __restrict__ Kh = K + (size_t)bh * SEQ * HD;
    const float* __restrict__ Vh = V + (size_t)bh * SEQ * HD;
    float* __restrict__       Oh = O + (size_t)bh * SEQ * HD;

    // ---- per-thread staging-role constants (2 rounds, round1 = +16 rows / +2 ko) ----
    const int key_s = lane >> 2;         // K rows key_s, key_s+16
    const int dgi   = lane & 3;          // K 16-float d group (both rounds)
    const int swk   = key_s & 7;         // (key_s+16)&7 == swk
    const int Ls    = lane & 31;         // V d-pair (both rounds)
    const int ko    = lane >> 5;         // V 8-key groups ko, ko+2
    const int swv   = Ls & 3;

    const float* kroot = Kh + (size_t)key_s * HD + dgi * 16;
    const float* vroot = Vh + (size_t)(ko * 8) * HD + 2 * Ls;

    f32x4  kst[2][4];    // prefetched K tile (2 rounds x 4 f32x4)
    float2 vst[2][8];    // prefetched V tile (2 rounds x 8 float2)

    #pragma unroll 1
    for (int half = 0; half < 2; ++half) {
        const int u  = half ? (63 - pu) : pu;   // strip index 0..63
        const int R0 = u * 32;                  // first query row
        const int nt = u + 1;                   // 32-key tiles in causal span

        // ---- Q fragments (B-operand layout), scale pre-folded ----
        bf16x8 qf[4];
        {
            const float* qrow = Qh + (size_t)(R0 + n) * HD;
            #pragma unroll
            for (int c = 0; c < 4; ++c) {
                f32x4 a = *(const f32x4*)(qrow + 16 * c + 8 * p);
                f32x4 b = *(const f32x4*)(qrow + 16 * c + 8 * p + 4);
                #pragma unroll
                for (int j = 0; j < 4; ++j) {
                    qf[c][j]     = (__bf16)(a[j] * SCALE);
                    qf[c][4 + j] = (__bf16)(b[j] * SCALE);
                }
            }
        }

        f32x16 oT[2] = {};      // O^T partial accumulators (d-halves)
        float  l_own = 0.f;     // partial row-sum (this lane's key columns)

        auto loadt = [&](int T) {   // global -> regs (tile T)
            const float* kp = kroot + (size_t)(32 * T) * HD;
            #pragma unroll
            for (int j = 0; j < 4; ++j) kst[0][j] = *(const f32x4*)(kp + 4 * j);
            #pragma unroll
            for (int j = 0; j < 4; ++j) kst[1][j] = *(const f32x4*)(kp + 1024 + 4 * j);
            const float* vp = vroot + (size_t)(32 * T) * HD;
            #pragma unroll
            for (int j = 0; j < 8; ++j) vst[0][j] = *(const float2*)(vp + (size_t)j * HD);
            #pragma unroll
            for (int j = 0; j < 8; ++j) vst[1][j] = *(const float2*)(vp + 1024 + (size_t)j * HD);
        };

        auto stage = [&](int b) {   // regs -> private LDS buf b (cvt; V transposed; swizzled)
            #pragma unroll
            for (int t = 0; t < 2; ++t) {
                const int ks = key_s + 16 * t;
                bf16x8 w0, w1;
                #pragma unroll
                for (int j = 0; j < 4; ++j) {
                    w0[j] = (__bf16)kst[t][0][j]; w0[4 + j] = (__bf16)kst[t][1][j];
                    w1[j] = (__bf16)kst[t][2][j]; w1[4 + j] = (__bf16)kst[t][3][j];
                }
                *(bf16x8*)KBw(wave, b, ks, (2 * dgi)     ^ swk) = w0;
                *(bf16x8*)KBw(wave, b, ks, (2 * dgi + 1) ^ swk) = w1;

                const int kot = ko + 2 * t;
                bf16x8 v0, v1;
                #pragma unroll
                for (int j = 0; j < 8; ++j) { v0[j] = (__bf16)vst[t][j].x; v1[j] = (__bf16)vst[t][j].y; }
                *(bf16x8*)VTw(wave, b, 2 * Ls,     kot ^ swv) = v0;
                *(bf16x8*)VTw(wave, b, 2 * Ls + 1, kot ^ swv) = v1;
            }
        };

        // ---- prologue: tile `wave` staged into buf0; tile wave+4 in regs ----
        if (wave < nt) {
            loadt(wave);
            stage(0);
            if (wave + 4 < nt) loadt(wave + 4);
        }
        int cur = 0;

        // ---- this wave's tiles, round-robin; NO barriers ----
        #pragma unroll 1
        for (int T = wave; T < nt; T += 4) {
            // 1) stage next tile (T+4) into the other buffer (regs -> LDS)
            if (T + 4 < nt) stage(cur ^ 1);
            // 2) prefetch tile T+8 into regs (issues early, lands next iter)
            if (T + 8 < nt) loadt(T + 8);

            // 3) compute tile T from buf[cur] (staged last iter / prologue)
            __builtin_amdgcn_s_setprio(1);
            f32x16 sT = {};
            #pragma unroll
            for (int cc = 0; cc < 4; ++cc) {
                bf16x8 kf = *(const bf16x8*)KBw(wave, cur, n, (2 * cc + p) ^ (n & 7));
                sT = __builtin_amdgcn_mfma_f32_32x32x16_bf16(kf, qf[cc], sT, 0, 0, 0);
            }

            const bool diag = (T == u);   // only the span's last tile is masked
            float pv[16];
            float ts = 0.f;
            #pragma unroll
            for (int r = 0; r < 16; ++r) {
                float pe = __builtin_amdgcn_exp2f(sT[r]);   // scale folded into Q
                if (diag) {
                    const int kk = (r & 3) + 8 * (r >> 2) + 4 * p;
                    pe = (kk <= n) ? pe : 0.f;
                }
                pv[r] = pe;
                ts += pe;
            }
            l_own += ts;

            // ---- P: C-layout -> B-layout in-register ----
            unsigned a0 = pk2(pv[0],  pv[1]),  a1 = pk2(pv[2],  pv[3]);
            unsigned a2 = pk2(pv[4],  pv[5]),  a3 = pk2(pv[6],  pv[7]);
            unsigned b0 = pk2(pv[8],  pv[9]),  b1 = pk2(pv[10], pv[11]);
            unsigned b2 = pk2(pv[12], pv[13]), b3 = pk2(pv[14], pv[15]);
            plswap(a0, a2);
            plswap(a1, a3);
            plswap(b0, b2);
            plswap(b1, b3);
            PU pu0, pu1;
            pu0.u[0] = a0; pu0.u[1] = a1; pu0.u[2] = a2; pu0.u[3] = a3;
            pu1.u[0] = b0; pu1.u[1] = b1; pu1.u[2] = b2; pu1.u[3] = b3;
            bf16x8 pf0 = pu0.v;
            bf16x8 pf1 = pu1.v;

            // ---- O^T += V^T P^T ----
            const int swn = (n >> 1) & 3;
            #pragma unroll
            for (int dg = 0; dg < 2; ++dg) {
                bf16x8 vf0 = *(const bf16x8*)VTw(wave, cur, 32 * dg + n, p ^ swn);
                bf16x8 vf1 = *(const bf16x8*)VTw(wave, cur, 32 * dg + n, (2 + p) ^ swn);
                oT[dg] = __builtin_amdgcn_mfma_f32_32x32x16_bf16(vf0, pf0, oT[dg], 0, 0, 0);
                oT[dg] = __builtin_amdgcn_mfma_f32_32x32x16_bf16(vf1, pf1, oT[dg], 0, 0, 0);
            }
            __builtin_amdgcn_s_setprio(0);

            cur ^= 1;
        }

        // ---- combine 4 key-quarter partials (additive: fixed-shift) ----
        float l_part = l_own + __shfl_xor(l_own, 32, 64);

        __syncthreads();                // staging dead; full fence (f32 reuse)
        if (wave != 3) {
            #pragma unroll
            for (int dg = 0; dg < 2; ++dg)
                #pragma unroll
                for (int r = 0; r < 16; ++r)
                    OSw(wave)[(dg * 16 + r) * 64 + lane] = oT[dg][r];
            OSw(wave)[2048 + lane] = l_part;
        }
        __syncthreads();                // partials visible
        if (wave == 3) {                // wave 3 always has the fewest tiles
            const float lsum = l_part + OSw(0)[2048 + lane]
                                      + OSw(1)[2048 + lane]
                                      + OSw(2)[2048 + lane];
            const float linv = 1.0f / lsum;
            #pragma unroll
            for (int dg = 0; dg < 2; ++dg) {
                #pragma unroll
                for (int u4 = 0; u4 < 4; ++u4) {
                    f32x4 o;
                    #pragma unroll
                    for (int j = 0; j < 4; ++j) {
                        const int r   = 4 * u4 + j;
                        const int idx = (dg * 16 + r) * 64 + lane;
                        o[j] = (oT[dg][r] + OSw(0)[idx] + OSw(1)[idx] + OSw(2)[idx]) * linv;
                    }
                    *(f32x4*)&Oh[(size_t)(R0 + n) * HD + dg * 32 + u4 * 8 + 4 * p] = o;
                }
            }
        }
        __syncthreads();                // scratch free before next strip stages
    }
}

extern "C" void kernel_launch(void* const* d_in, const int* in_sizes, int n_in,
                              void* d_out, int out_size, void* d_ws, size_t ws_size,
                              hipStream_t stream) {
    const float* Q = (const float*)d_in[0];
    const float* K = (const float*)d_in[1];
    const float* V = (const float*)d_in[2];
    // d_in[3]: causal mask — analytically tril, not read.
    float* O = (float*)d_out;

    dim3 grid(1024);
    dim3 block(256);
    attn_fwd<<<grid, block, 0, stream>>>(Q, K, V, O);
}